// Round 1
// baseline (198.932 us; speedup 1.0000x reference)
//
#include <hip/hip_runtime.h>
#include <math.h>

#define N_SPK 512
#define N_UTT 32
#define DIM   512
#define EPSN  1e-8f

// Kernel 1: per-speaker centroid (mean over U), L2-normalize, store K-MAJOR:
// cnT[k*N_SPK + c] = c_n[c][k]  (so the GEMM's B reads coalesce over c).
__global__ __launch_bounds__(256) void centroid_kernel(
    const float* __restrict__ emb, float* __restrict__ cnT) {
  int j = blockIdx.x;       // speaker
  int t = threadIdx.x;      // 256 threads; thread owns dims t and t+256
  const float* base = emb + (size_t)j * N_UTT * DIM;
  float s0 = 0.f, s1 = 0.f;
#pragma unroll
  for (int u = 0; u < N_UTT; ++u) {
    s0 += base[u * DIM + t];
    s1 += base[u * DIM + t + 256];
  }
  s0 *= (1.f / N_UTT);
  s1 *= (1.f / N_UTT);
  float ss = s0 * s0 + s1 * s1;
#pragma unroll
  for (int off = 32; off > 0; off >>= 1) ss += __shfl_xor(ss, off, 64);
  __shared__ float red[4];
  if ((t & 63) == 0) red[t >> 6] = ss;
  __syncthreads();
  float total = red[0] + red[1] + red[2] + red[3];
  float inv = 1.f / fmaxf(sqrtf(total), EPSN);
  cnT[(size_t)t * N_SPK + j] = s0 * inv;
  cnT[(size_t)(t + 256) * N_SPK + j] = s1 * inv;
}

// Kernel 2: one block per speaker j.
//  - stage E_j (32x512 fp32 = 64KB) in LDS, L2-normalize rows in place
//  - register-tiled GEMM: each thread computes 8 rows x 8 centroids
//    (tr = t&3 picks row-group, tc = t>>2 picks centroid-group)
//  - epilogue: logits = w*sim+b written back into the same LDS,
//    per-row wave LSE + diag pick, atomicAdd of (lse - diag)/(N*U).
__global__ __launch_bounds__(256, 2) void ge2e_kernel(
    const float* __restrict__ emb, const float* __restrict__ cnT,
    const float* __restrict__ wp, const float* __restrict__ bp,
    float* __restrict__ out) {
  __shared__ float E[N_UTT * DIM];  // exactly 65536 B (static LDS cap)
  int j = blockIdx.x;
  int t = threadIdx.x;
  int lane = t & 63, wid = t >> 6;

  // ---- stage E (float4, coalesced) ----
  const float4* src = (const float4*)(emb + (size_t)j * N_UTT * DIM);
  float4* Ev = (float4*)E;
#pragma unroll
  for (int i = 0; i < 16; ++i) Ev[t + 256 * i] = src[t + 256 * i];
  __syncthreads();

  // ---- normalize rows in place; wave wid owns rows wid*8..wid*8+7 ----
#pragma unroll
  for (int r8 = 0; r8 < 8; ++r8) {
    int r = wid * 8 + r8;
    float v[8];
    float ss = 0.f;
#pragma unroll
    for (int i = 0; i < 8; ++i) {
      v[i] = E[r * DIM + lane + 64 * i];
      ss += v[i] * v[i];
    }
#pragma unroll
    for (int off = 32; off > 0; off >>= 1) ss += __shfl_xor(ss, off, 64);
    float inv = 1.f / fmaxf(sqrtf(ss), EPSN);
#pragma unroll
    for (int i = 0; i < 8; ++i) E[r * DIM + lane + 64 * i] = v[i] * inv;
  }
  __syncthreads();

  // ---- GEMM: acc[ri][ci] = sum_k E[r0+ri][k] * cnT[k][c0+ci] ----
  int tr = t & 3, tc = t >> 2;
  int r0 = tr * 8, c0 = tc * 8;
  float acc[8][8];
#pragma unroll
  for (int ri = 0; ri < 8; ++ri)
#pragma unroll
    for (int ci = 0; ci < 8; ++ci) acc[ri][ci] = 0.f;

#pragma unroll 4
  for (int k = 0; k < DIM; ++k) {
    const float4* cp = (const float4*)(cnT + (size_t)k * N_SPK + c0);
    float4 ca = cp[0], cb = cp[1];
    float cv[8] = {ca.x, ca.y, ca.z, ca.w, cb.x, cb.y, cb.z, cb.w};
    float ev[8];
#pragma unroll
    for (int ri = 0; ri < 8; ++ri) ev[ri] = E[(r0 + ri) * DIM + k];
#pragma unroll
    for (int ri = 0; ri < 8; ++ri)
#pragma unroll
      for (int ci = 0; ci < 8; ++ci)
        acc[ri][ci] = fmaf(ev[ri], cv[ci], acc[ri][ci]);
  }
  __syncthreads();  // all E reads done before we overwrite with logits

  float w = *wp, b = *bp;
#pragma unroll
  for (int ri = 0; ri < 8; ++ri)
#pragma unroll
    for (int ci = 0; ci < 8; ++ci)
      E[(r0 + ri) * DIM + c0 + ci] = fmaf(w, acc[ri][ci], b);
  __syncthreads();

  // ---- per-row LSE + diag; wave wid owns rows wid*8..wid*8+7 ----
  float partial = 0.f;
#pragma unroll
  for (int r8 = 0; r8 < 8; ++r8) {
    int r = wid * 8 + r8;
    float v[8], m = -INFINITY;
#pragma unroll
    for (int i = 0; i < 8; ++i) {
      v[i] = E[r * DIM + lane + 64 * i];
      m = fmaxf(m, v[i]);
    }
#pragma unroll
    for (int off = 32; off > 0; off >>= 1) m = fmaxf(m, __shfl_xor(m, off, 64));
    float s = 0.f;
#pragma unroll
    for (int i = 0; i < 8; ++i) s += __expf(v[i] - m);
#pragma unroll
    for (int off = 32; off > 0; off >>= 1) s += __shfl_xor(s, off, 64);
    float lse = m + __logf(s);
    float diag = E[r * DIM + j];  // logit at column j (own speaker)
    partial += lse - diag;        // -logp_diag for this row
  }
  if (lane == 0) atomicAdd(out, partial * (1.f / (N_SPK * N_UTT)));
}

extern "C" void kernel_launch(void* const* d_in, const int* in_sizes, int n_in,
                              void* d_out, int out_size, void* d_ws, size_t ws_size,
                              hipStream_t stream) {
  const float* emb = (const float*)d_in[0];
  const float* wp  = (const float*)d_in[1];
  const float* bp  = (const float*)d_in[2];
  float* out = (float*)d_out;
  float* cnT = (float*)d_ws;  // 512*512 fp32 = 1 MB scratch

  hipMemsetAsync(d_out, 0, sizeof(float), stream);  // d_ws/d_out arrive poisoned
  centroid_kernel<<<N_SPK, 256, 0, stream>>>(emb, cnT);
  ge2e_kernel<<<N_SPK, 256, 0, stream>>>(emb, cnT, wp, bp, out);
}

// Round 2
// 114.574 us; speedup vs baseline: 1.7363x; 1.7363x over previous
//
#include <hip/hip_runtime.h>
#include <math.h>

#define N_SPK 512
#define N_UTT 32
#define DIM   512
#define EPSN  1e-8f

typedef __attribute__((ext_vector_type(8))) short  short8;  // 8 bf16 = 4 VGPR
typedef __attribute__((ext_vector_type(4))) float  f32x4;   // MFMA C/D

// fp32 -> bf16 round-to-nearest-even
__device__ inline unsigned short f2bf(float x) {
  unsigned int u = __builtin_bit_cast(unsigned int, x);
  unsigned int r = (u + 0x7fffu + ((u >> 16) & 1u)) >> 16;
  return (unsigned short)r;
}

// Kernel 1: centroid (mean over U), L2-normalize in fp32, write bf16
// ROW-MAJOR cn[c][k] — coalesced, and exactly the MFMA B-operand order
// (lane n reads 8 consecutive k). Old version's k-major fp32 scatter
// (2KB-stride dword writes) is gone.
__global__ __launch_bounds__(256) void centroid_kernel(
    const float* __restrict__ emb, unsigned short* __restrict__ cn) {
  int j = blockIdx.x;
  int t = threadIdx.x;  // owns dims t and t+256
  const float* base = emb + (size_t)j * N_UTT * DIM;
  float s0 = 0.f, s1 = 0.f;
#pragma unroll
  for (int u = 0; u < N_UTT; ++u) {
    s0 += base[u * DIM + t];
    s1 += base[u * DIM + t + 256];
  }
  s0 *= (1.f / N_UTT);
  s1 *= (1.f / N_UTT);
  float ss = s0 * s0 + s1 * s1;
#pragma unroll
  for (int off = 32; off > 0; off >>= 1) ss += __shfl_xor(ss, off, 64);
  __shared__ float red[4];
  if ((t & 63) == 0) red[t >> 6] = ss;
  __syncthreads();
  float total = red[0] + red[1] + red[2] + red[3];
  float inv = 1.f / fmaxf(sqrtf(total), EPSN);
  cn[(size_t)j * DIM + t]       = f2bf(s0 * inv);
  cn[(size_t)j * DIM + t + 256] = f2bf(s1 * inv);
}

// Kernel 2: one block per speaker j. 4 waves; wave w owns columns
// w*128..w*128+127 (8 N-tiles of 16). MFMA 16x16x32 bf16.
// E tile (32x512 bf16, 32KB) is XOR-swizzled in 16B chunks:
// chunk c of row r lives at position c ^ (r&7)  → both ds_write_b128
// (staging) and ds_read_b128 (A-frag) run at the LDS structural floor
// (natural layout serializes 16 rows onto 4 banks = 2x waste).
__global__ __launch_bounds__(256, 3) void ge2e_kernel(
    const float* __restrict__ emb, const unsigned short* __restrict__ cn,
    const float* __restrict__ wp, const float* __restrict__ bp,
    float* __restrict__ out) {
  __shared__ __align__(16) unsigned short E[N_UTT * DIM];  // 32 KB
  __shared__ float red[4][N_UTT][2];                       // 1 KB (m, s)
  __shared__ float dred[4];

  int j = blockIdx.x;
  int t = threadIdx.x;
  int lane = t & 63, wid = t >> 6;
  int n15 = lane & 15, quad = lane >> 4;

  // ---- stage + fp32 normalize + bf16 pack; wave wid owns rows wid*8.. ----
#pragma unroll
  for (int r8 = 0; r8 < 8; ++r8) {
    int r = wid * 8 + r8;
    const float* rp = emb + ((size_t)j * N_UTT + r) * DIM + lane * 8;
    float4 v0 = *(const float4*)rp;
    float4 v1 = *(const float4*)(rp + 4);
    float ss = v0.x * v0.x + v0.y * v0.y + v0.z * v0.z + v0.w * v0.w +
               v1.x * v1.x + v1.y * v1.y + v1.z * v1.z + v1.w * v1.w;
#pragma unroll
    for (int off = 32; off > 0; off >>= 1) ss += __shfl_xor(ss, off, 64);
    float inv = 1.f / fmaxf(sqrtf(ss), EPSN);
    short8 pk;
    pk[0] = (short)f2bf(v0.x * inv); pk[1] = (short)f2bf(v0.y * inv);
    pk[2] = (short)f2bf(v0.z * inv); pk[3] = (short)f2bf(v0.w * inv);
    pk[4] = (short)f2bf(v1.x * inv); pk[5] = (short)f2bf(v1.y * inv);
    pk[6] = (short)f2bf(v1.z * inv); pk[7] = (short)f2bf(v1.w * inv);
    int sw = lane ^ (r & 7);  // chunk index = lane (each lane wrote 16B)
    *(short8*)&E[r * DIM + sw * 8] = pk;
  }
  __syncthreads();

  // ---- MFMA GEMM: sim[r][c] = E_n[r][:] . cn[c][:] ----
  f32x4 acc[2][8];
#pragma unroll
  for (int mt = 0; mt < 2; ++mt)
#pragma unroll
    for (int nt = 0; nt < 8; ++nt) acc[mt][nt] = (f32x4){0.f, 0.f, 0.f, 0.f};

  for (int ks = 0; ks < 16; ++ks) {
    short8 b[8];
#pragma unroll
    for (int nt = 0; nt < 8; ++nt) {
      int c = wid * 128 + nt * 16 + n15;          // B[n][k]: lane=n, 8 k's
      b[nt] = *(const short8*)(cn + (size_t)c * DIM + ks * 32 + quad * 8);
    }
    short8 a[2];
#pragma unroll
    for (int mt = 0; mt < 2; ++mt) {
      int r = mt * 16 + n15;                      // A[m][k]: lane=m, 8 k's
      int sw = (ks * 4 + quad) ^ (r & 7);
      a[mt] = *(const short8*)&E[r * DIM + sw * 8];
    }
#pragma unroll
    for (int mt = 0; mt < 2; ++mt)
#pragma unroll
      for (int nt = 0; nt < 8; ++nt)
        acc[mt][nt] = __builtin_amdgcn_mfma_f32_16x16x32_bf16(
            a[mt], b[nt], acc[mt][nt], 0, 0, 0);
  }

  // ---- epilogue: logits = w*sim+b, fused LSE + diag ----
  float w = *wp, bb = *bp;
  float dsum = 0.f;  // sum of diag logits held by this lane (col == j)
#pragma unroll
  for (int mt = 0; mt < 2; ++mt)
#pragma unroll
    for (int nt = 0; nt < 8; ++nt) {
      int c = wid * 128 + nt * 16 + n15;
      bool isdiag = (c == j);
#pragma unroll
      for (int rg = 0; rg < 4; ++rg) {
        float v = fmaf(w, acc[mt][nt][rg], bb);
        acc[mt][nt][rg] = v;
        if (isdiag) dsum += v;
      }
    }

  // per-row (row = mt*16 + quad*4 + rg) max/sum over this wave's 128 cols:
  // 8 local values + shuffle across the 16 lanes of the quad (xor 1,2,4,8)
#pragma unroll
  for (int mt = 0; mt < 2; ++mt)
#pragma unroll
    for (int rg = 0; rg < 4; ++rg) {
      float m = -INFINITY;
#pragma unroll
      for (int nt = 0; nt < 8; ++nt) m = fmaxf(m, acc[mt][nt][rg]);
#pragma unroll
      for (int off = 1; off < 16; off <<= 1) m = fmaxf(m, __shfl_xor(m, off, 64));
      float s = 0.f;
#pragma unroll
      for (int nt = 0; nt < 8; ++nt) s += __expf(acc[mt][nt][rg] - m);
#pragma unroll
      for (int off = 1; off < 16; off <<= 1) s += __shfl_xor(s, off, 64);
      if (n15 == 0) {
        int r = mt * 16 + quad * 4 + rg;
        red[wid][r][0] = m;
        red[wid][r][1] = s;
      }
    }
#pragma unroll
  for (int off = 32; off > 0; off >>= 1) dsum += __shfl_xor(dsum, off, 64);
  if (lane == 0) dred[wid] = dsum;
  __syncthreads();

  // combine 4 wave-partials per row; rows 0..31 on threads 0..31 (wave 0)
  if (t < 32) {
    float M = -INFINITY;
#pragma unroll
    for (int ww = 0; ww < 4; ++ww) M = fmaxf(M, red[ww][t][0]);
    float S = 0.f;
#pragma unroll
    for (int ww = 0; ww < 4; ++ww) S += red[ww][t][1] * __expf(red[ww][t][0] - M);
    float lse = M + __logf(S);
#pragma unroll
    for (int off = 16; off > 0; off >>= 1) lse += __shfl_xor(lse, off, 64);
    if (t == 0) {
      float tot = lse - (dred[0] + dred[1] + dred[2] + dred[3]);
      atomicAdd(out, tot * (1.f / (N_SPK * N_UTT)));
    }
  }
}

extern "C" void kernel_launch(void* const* d_in, const int* in_sizes, int n_in,
                              void* d_out, int out_size, void* d_ws, size_t ws_size,
                              hipStream_t stream) {
  const float* emb = (const float*)d_in[0];
  const float* wp  = (const float*)d_in[1];
  const float* bp  = (const float*)d_in[2];
  float* out = (float*)d_out;
  unsigned short* cn = (unsigned short*)d_ws;  // 512*512 bf16 = 512 KB

  hipMemsetAsync(d_out, 0, sizeof(float), stream);
  centroid_kernel<<<N_SPK, 256, 0, stream>>>(emb, cn);
  ge2e_kernel<<<N_SPK, 256, 0, stream>>>(emb, cn, wp, bp, out);
}

// Round 3
// 97.333 us; speedup vs baseline: 2.0438x; 1.1771x over previous
//
#include <hip/hip_runtime.h>
#include <math.h>

#define N_SPK 512
#define N_UTT 32
#define DIM   512
#define EPSN  1e-8f

typedef __attribute__((ext_vector_type(8))) short  short8;  // 8 bf16 = 4 VGPR
typedef __attribute__((ext_vector_type(4))) float  f32x4;   // MFMA C/D

// fp32 -> bf16 round-to-nearest-even
__device__ inline unsigned short f2bf(float x) {
  unsigned int u = __builtin_bit_cast(unsigned int, x);
  unsigned int r = (u + 0x7fffu + ((u >> 16) & 1u)) >> 16;
  return (unsigned short)r;
}

// ws layout: [0, 512KB) = cnk (bf16, K-chunked); [512KB, +2KB) = block partials
#define CNK_ELEMS (N_SPK * DIM)

// Kernel 1: centroid (mean over U) + L2-normalize (fp32) -> bf16, stored
// K-CHUNKED: cnk[(kc*N_SPK + c)*32 + (k&31)], kc = k/32. This makes the
// GEMM's B-fragment loads (16 cols x 64B) land in a CONTIGUOUS 1KB run per
// instruction -> full cache-line use (R2's layout fetched 16 scattered
// half-lines per load and thrashed L1).
// Reads are float4-coalesced (R2 used 64 scalar stride-2KB loads/thread).
__global__ __launch_bounds__(256) void centroid_kernel(
    const float* __restrict__ emb, unsigned short* __restrict__ cnk) {
  int j = blockIdx.x, t = threadIdx.x;
  int c4 = t & 127, half = t >> 7;  // c4: which float4 of the row (128/row)
  const float4* base = (const float4*)(emb + (size_t)j * N_UTT * DIM);
  float4 s = {0.f, 0.f, 0.f, 0.f};
#pragma unroll
  for (int u = 0; u < 16; ++u) {
    float4 v = base[(half + 2 * u) * 128 + c4];
    s.x += v.x; s.y += v.y; s.z += v.z; s.w += v.w;
  }
  __shared__ float4 comb[128];
  if (half) comb[c4] = s;
  __syncthreads();
  float4 m = {0.f, 0.f, 0.f, 0.f};
  float ss = 0.f;
  if (!half) {
    float4 o = comb[c4];
    m.x = (s.x + o.x) * (1.f / N_UTT);
    m.y = (s.y + o.y) * (1.f / N_UTT);
    m.z = (s.z + o.z) * (1.f / N_UTT);
    m.w = (s.w + o.w) * (1.f / N_UTT);
    ss = m.x * m.x + m.y * m.y + m.z * m.z + m.w * m.w;
  }
#pragma unroll
  for (int off = 32; off > 0; off >>= 1) ss += __shfl_xor(ss, off, 64);
  __shared__ float red[4];
  if ((t & 63) == 0) red[t >> 6] = ss;
  __syncthreads();
  float total = red[0] + red[1] + red[2] + red[3];
  float inv = 1.f / fmaxf(sqrtf(total), EPSN);
  if (!half) {
    int d0 = c4 * 4;          // first of this thread's 4 dims
    int kc = d0 >> 5;         // k-chunk
    unsigned short* p = cnk + ((size_t)kc * N_SPK + j) * 32 + (d0 & 31);
    p[0] = f2bf(m.x * inv); p[1] = f2bf(m.y * inv);
    p[2] = f2bf(m.z * inv); p[3] = f2bf(m.w * inv);
  }
}

// Kernel 2: one block per speaker j, 512 threads (8 waves; wave owns 64
// cols -> 4 waves/SIMD at grid=512, double R2's latency hiding).
// E tile (32x512 bf16, 32KB) XOR-swizzled as in R2. B-frags read straight
// from the contiguous cnk layout (no LDS staging needed). Per-block loss
// partial written to ws (no same-address atomics -> no serialized RMW tail).
__global__ __launch_bounds__(512, 4) void ge2e_kernel(
    const float* __restrict__ emb, const unsigned short* __restrict__ cnk,
    const float* __restrict__ wp, const float* __restrict__ bp,
    float* __restrict__ partials) {
  __shared__ __align__(16) unsigned short E[N_UTT * DIM];  // 32 KB
  __shared__ float red[8][N_UTT][2];                       // 2 KB (m, s)
  __shared__ float dred[8];

  int j = blockIdx.x;
  int t = threadIdx.x;
  int lane = t & 63, wid = t >> 6;
  int n15 = lane & 15, quad = lane >> 4;

  // ---- stage + fp32 normalize + bf16 pack; wave wid owns rows wid*4.. ----
#pragma unroll
  for (int r8 = 0; r8 < 4; ++r8) {
    int r = wid * 4 + r8;
    const float* rp = emb + ((size_t)j * N_UTT + r) * DIM + lane * 8;
    float4 v0 = *(const float4*)rp;
    float4 v1 = *(const float4*)(rp + 4);
    float ss = v0.x * v0.x + v0.y * v0.y + v0.z * v0.z + v0.w * v0.w +
               v1.x * v1.x + v1.y * v1.y + v1.z * v1.z + v1.w * v1.w;
#pragma unroll
    for (int off = 32; off > 0; off >>= 1) ss += __shfl_xor(ss, off, 64);
    float inv = 1.f / fmaxf(sqrtf(ss), EPSN);
    short8 pk;
    pk[0] = (short)f2bf(v0.x * inv); pk[1] = (short)f2bf(v0.y * inv);
    pk[2] = (short)f2bf(v0.z * inv); pk[3] = (short)f2bf(v0.w * inv);
    pk[4] = (short)f2bf(v1.x * inv); pk[5] = (short)f2bf(v1.y * inv);
    pk[6] = (short)f2bf(v1.z * inv); pk[7] = (short)f2bf(v1.w * inv);
    int sw = lane ^ (r & 7);
    *(short8*)&E[r * DIM + sw * 8] = pk;
  }
  __syncthreads();

  // ---- MFMA GEMM: wave wid computes rows 0..31 x cols wid*64..+63 ----
  f32x4 acc[2][4];
#pragma unroll
  for (int mt = 0; mt < 2; ++mt)
#pragma unroll
    for (int nt = 0; nt < 4; ++nt) acc[mt][nt] = (f32x4){0.f, 0.f, 0.f, 0.f};

  for (int ks = 0; ks < 16; ++ks) {
    short8 b[4];
#pragma unroll
    for (int nt = 0; nt < 4; ++nt) {
      int c = wid * 64 + nt * 16 + n15;  // B[n][k]: lane=col, quad*8 k's
      b[nt] = *(const short8*)(cnk + ((size_t)ks * N_SPK + c) * 32 + quad * 8);
    }
    short8 a[2];
#pragma unroll
    for (int mt = 0; mt < 2; ++mt) {
      int r = mt * 16 + n15;
      int sw = (ks * 4 + quad) ^ (r & 7);
      a[mt] = *(const short8*)&E[r * DIM + sw * 8];
    }
#pragma unroll
    for (int mt = 0; mt < 2; ++mt)
#pragma unroll
      for (int nt = 0; nt < 4; ++nt)
        acc[mt][nt] = __builtin_amdgcn_mfma_f32_16x16x32_bf16(
            a[mt], b[nt], acc[mt][nt], 0, 0, 0);
  }

  // ---- epilogue: logits = w*sim+b, fused LSE + diag ----
  float w = *wp, bb = *bp;
  float dsum = 0.f;
#pragma unroll
  for (int mt = 0; mt < 2; ++mt)
#pragma unroll
    for (int nt = 0; nt < 4; ++nt) {
      int c = wid * 64 + nt * 16 + n15;
      bool isdiag = (c == j);
#pragma unroll
      for (int rg = 0; rg < 4; ++rg) {
        float v = fmaf(w, acc[mt][nt][rg], bb);
        acc[mt][nt][rg] = v;
        if (isdiag) dsum += v;
      }
    }

#pragma unroll
  for (int mt = 0; mt < 2; ++mt)
#pragma unroll
    for (int rg = 0; rg < 4; ++rg) {
      float m = -INFINITY;
#pragma unroll
      for (int nt = 0; nt < 4; ++nt) m = fmaxf(m, acc[mt][nt][rg]);
#pragma unroll
      for (int off = 1; off < 16; off <<= 1) m = fmaxf(m, __shfl_xor(m, off, 64));
      float s = 0.f;
#pragma unroll
      for (int nt = 0; nt < 4; ++nt) s += __expf(acc[mt][nt][rg] - m);
#pragma unroll
      for (int off = 1; off < 16; off <<= 1) s += __shfl_xor(s, off, 64);
      if (n15 == 0) {
        int r = mt * 16 + quad * 4 + rg;
        red[wid][r][0] = m;
        red[wid][r][1] = s;
      }
    }
#pragma unroll
  for (int off = 32; off > 0; off >>= 1) dsum += __shfl_xor(dsum, off, 64);
  if (lane == 0) dred[wid] = dsum;
  __syncthreads();

  // combine 8 wave-partials per row; rows 0..31 on threads 0..31 (wave 0)
  if (t < 32) {
    float M = -INFINITY;
#pragma unroll
    for (int ww = 0; ww < 8; ++ww) M = fmaxf(M, red[ww][t][0]);
    float S = 0.f;
#pragma unroll
    for (int ww = 0; ww < 8; ++ww) S += red[ww][t][1] * __expf(red[ww][t][0] - M);
    float lse = M + __logf(S);
#pragma unroll
    for (int off = 16; off > 0; off >>= 1) lse += __shfl_xor(lse, off, 64);
    if (t == 0) {
      float d = dred[0] + dred[1] + dred[2] + dred[3] +
                dred[4] + dred[5] + dred[6] + dred[7];
      partials[j] = lse - d;  // one plain store; no atomics
    }
  }
}

// Kernel 3: reduce the 512 per-block partials -> the loss scalar.
__global__ __launch_bounds__(512) void finalize_kernel(
    const float* __restrict__ partials, float* __restrict__ out) {
  int t = threadIdx.x;
  float v = partials[t];
#pragma unroll
  for (int off = 32; off > 0; off >>= 1) v += __shfl_xor(v, off, 64);
  __shared__ float r[8];
  if ((t & 63) == 0) r[t >> 6] = v;
  __syncthreads();
  if (t == 0) {
    float s = r[0] + r[1] + r[2] + r[3] + r[4] + r[5] + r[6] + r[7];
    out[0] = s * (1.f / (N_SPK * N_UTT));
  }
}

extern "C" void kernel_launch(void* const* d_in, const int* in_sizes, int n_in,
                              void* d_out, int out_size, void* d_ws, size_t ws_size,
                              hipStream_t stream) {
  const float* emb = (const float*)d_in[0];
  const float* wp  = (const float*)d_in[1];
  const float* bp  = (const float*)d_in[2];
  float* out = (float*)d_out;
  unsigned short* cnk = (unsigned short*)d_ws;              // 512 KB
  float* partials = (float*)((char*)d_ws + (size_t)CNK_ELEMS * 2);  // 2 KB

  centroid_kernel<<<N_SPK, 256, 0, stream>>>(emb, cnk);
  ge2e_kernel<<<N_SPK, 512, 0, stream>>>(emb, cnk, wp, bp, partials);
  finalize_kernel<<<1, 512, 0, stream>>>(partials, out);
}